// Round 2
// baseline (371.237 us; speedup 1.0000x reference)
//
#include <hip/hip_runtime.h>

#define WIN    11
#define IMG    512
#define CH     66              // output rows per block (6*11 -> static slot mapping)
#define NCHUNK 8               // ceil(512/66)
#define PITCH  528             // dwords per ring row: 5 left pad + 512 + 11 right pad
#define FSTRIDE (WIN*PITCH)    // 5808 dwords per field plane (ring depth 11)
#define VBUF_DW (5*FSTRIDE)    // 29040 dwords = 116,160 B LDS
#define NT     512

// XOR byte-address swizzle: fold byte bits 7-9 into bank bits 4-6.
// Applied identically on write and read (bijective within each 128B block),
// breaks the 16-way conflict of the stride-32B h-phase read pattern.
__device__ __forceinline__ unsigned swz(unsigned b) {
    return b ^ ((b >> 3) & 0x70u);
}

// ---------------------------------------------------------------------------
// v-first streaming SSIM: one block = 512 cols x 66 output rows of one plane.
// Vertical 11-tap in registers (11 in-flight accumulators x 5 fields),
// horizontal 11-tap from an 11-row LDS ring via swizzled ds_read_b128.
// ---------------------------------------------------------------------------
__global__ __launch_bounds__(NT, 2)
void ssim_stream_kernel(const float* __restrict__ x,
                        const float* __restrict__ y,
                        const float* __restrict__ kern,
                        float* __restrict__ accum)
{
    __shared__ float vbuf[VBUF_DW];
    __shared__ float wsum[NT/64];

    const int tid   = threadIdx.x;
    const int plane = blockIdx.x >> 3;
    const int chunk = blockIdx.x & 7;
    const int r0    = chunk * CH;          // r0 % 11 == 0  (66 = 6*11)

    const float* xp = x + (size_t)plane * (IMG*IMG);
    const float* yp = y + (size_t)plane * (IMG*IMG);

    // 1D separable weights: w[i] = k2[i][5] / sqrt(k2[5][5])
    float w[WIN];
    {
        const float cinv = rsqrtf(kern[5*WIN+5]);
        #pragma unroll
        for (int i = 0; i < WIN; ++i) w[i] = kern[i*WIN+5] * cinv;
    }

    // zero ring (incl. pads; pads are never overwritten -> stay zero)
    for (int idx = tid; idx < VBUF_DW; idx += NT) vbuf[idx] = 0.f;
    __syncthreads();

    // 5 fields x 11 in-flight vertical accumulators (all static-indexed)
    float acc[5][WIN];
    #pragma unroll
    for (int f = 0; f < 5; ++f)
        #pragma unroll
        for (int s = 0; s < WIN; ++s) acc[f][s] = 0.f;

    float lsum = 0.f;
    char* vb = (char*)vbuf;

    for (int g = 0; g < 7; ++g) {          // 7 groups of 11 input rows = 77 rows
        #pragma unroll
        for (int m = 0; m < WIN; ++m) {    // static phase within group
            const int i = r0 - 5 + 11*g + m;     // input row (zero-padded)
            float vx = 0.f, vy = 0.f;
            if ((unsigned)i < IMG) {
                vx = xp[(size_t)i*IMG + tid];
                vy = yp[(size_t)i*IMG + tid];
            }
            const float vxx = vx*vx, vyy = vy*vy, vxy = vx*vy;
            // i % 11 == (6+m) % 11  ->  slot s gets weight w[(m+11-s)%11]
            #pragma unroll
            for (int s = 0; s < WIN; ++s) {
                const float wk = w[(m + WIN - s) % WIN];
                acc[0][s] += wk * vx;
                acc[1][s] += wk * vy;
                acc[2][s] += wk * vxx;
                acc[3][s] += wk * vyy;
                acc[4][s] += wk * vxy;
            }
            // slot (m+1)%11 just completed output row rl = 11g + m - 10
            const int cs = (m + 1) % WIN;        // compile-time
            const int rl = 11*g + m - 10;
            if (rl >= 0 && rl < CH) {
                const int rr = rl % WIN;         // ring row
                const unsigned dbase = (unsigned)(rr*PITCH + 5 + tid);
                #pragma unroll
                for (int f = 0; f < 5; ++f) {
                    const unsigned byte = (dbase + f*FSTRIDE) * 4u;
                    *(float*)(vb + swz(byte)) = acc[f][cs];
                }
            }
            #pragma unroll
            for (int f = 0; f < 5; ++f) acc[f][cs] = 0.f;
        }

        // ---- horizontal phase over the rows completed in this group ----
        const int rllo = (g == 0) ? 0 : 11*g - 10;
        const int rlhi = (11*g < CH) ? 11*g : CH - 1;
        const int ntasks = (rlhi - rllo + 1) * 64;   // 64 octs per row
        __syncthreads();
        for (int task = tid; task < ntasks; task += NT) {
            const int o    = task & 63;              // oct: output cols 8o..8o+7
            const int rid  = rllo + (task >> 6);
            const int orow = r0 + rid;
            if (orow < IMG) {
                const int rr = rid % WIN;
                float res[5][8];
                #pragma unroll
                for (int f = 0; f < 5; ++f) {
                    float win[20];
                    const unsigned d0 = (unsigned)(f*FSTRIDE + rr*PITCH + 8*o);
                    #pragma unroll
                    for (int j = 0; j < 5; ++j) {    // 5 x ds_read_b128
                        const unsigned byte = (d0 + 4u*j) * 4u;
                        const float4 q = *(const float4*)(vb + swz(byte));
                        win[4*j+0] = q.x; win[4*j+1] = q.y;
                        win[4*j+2] = q.z; win[4*j+3] = q.w;
                    }
                    #pragma unroll
                    for (int j = 0; j < 8; ++j) {
                        float s = 0.f;
                        #pragma unroll
                        for (int k = 0; k < WIN; ++k) s += w[k] * win[j+k];
                        res[f][j] = s;
                    }
                }
                #pragma unroll
                for (int j = 0; j < 8; ++j) {
                    const float mx = res[0][j], my = res[1][j];
                    const float mxx = mx*mx, myy = my*my, mxy = mx*my;
                    const float sxx = res[2][j] - mxx;
                    const float syy = res[3][j] - myy;
                    const float sxy = res[4][j] - mxy;
                    const float num = (2.f*mxy + 1e-4f) * (2.f*sxy + 9e-4f);
                    const float den = (mxx + myy + 1e-4f) * (sxx + syy + 9e-4f);
                    lsum += num * __builtin_amdgcn_rcpf(den);
                }
            }
        }
        __syncthreads();
    }

    // ---- block reduction + one atomic per block ----
    #pragma unroll
    for (int off = 32; off > 0; off >>= 1)
        lsum += __shfl_down(lsum, off, 64);
    if ((tid & 63) == 0) wsum[tid >> 6] = lsum;
    __syncthreads();
    if (tid == 0) {
        float s = 0.f;
        #pragma unroll
        for (int k = 0; k < NT/64; ++k) s += wsum[k];
        atomicAdd(accum, s);
    }
}

__global__ void ssim_finalize(const float* __restrict__ accum,
                              float* __restrict__ out, float invN)
{
    out[0] = 1.0f - accum[0] * invN;
}

extern "C" void kernel_launch(void* const* d_in, const int* in_sizes, int n_in,
                              void* d_out, int out_size, void* d_ws, size_t ws_size,
                              hipStream_t stream)
{
    const float* x    = (const float*)d_in[0];
    const float* y    = (const float*)d_in[1];
    const float* kern = (const float*)d_in[2];
    float* out   = (float*)d_out;
    float* accum = (float*)d_ws;

    const int planes = in_sizes[0] / (IMG*IMG);   // B*C = 64

    hipMemsetAsync(accum, 0, sizeof(float), stream);
    ssim_stream_kernel<<<planes*NCHUNK, NT, 0, stream>>>(x, y, kern, accum);
    ssim_finalize<<<1, 1, 0, stream>>>(accum, out,
                                       1.0f / ((float)planes * IMG * IMG));
}